// Round 11
// baseline (230.664 us; speedup 1.0000x reference)
//
#include <hip/hip_runtime.h>

#define D 64
#define SCAN_CHUNK 1024
#define NXCD 8
#define NPB 192          // nodes per bucket (CSR build)
#define NBMAX 1024       // max buckets for tier-0
#define CAP 4096         // bucket capacity (mean 2400 here; 34 sigma headroom)
#define ECHUNK 4096      // edges per bucket_sort block
#define NPT 64           // nodes per fused agg+mlp block (4 MFMA tiles)
#define HSTR 72          // LDS row stride (ushorts): 16B-aligned, bank-skewed

typedef unsigned short ushort_t;
typedef __bf16 bf16_t;
typedef __bf16 bf16x8 __attribute__((ext_vector_type(8)));
typedef float f32x4 __attribute__((ext_vector_type(4)));

__device__ __forceinline__ ushort_t f2bf(float v) {
    unsigned u = __float_as_uint(v);
    return (ushort_t)((u + 0x7FFF + ((u >> 16) & 1)) >> 16);
}
__device__ __forceinline__ float bf2f(ushort_t h) {
    return __uint_as_float((unsigned)h << 16);
}

// ---------------------------------------------------------------------------
// d_ws layout (tier 0):
//   gcnt[int,1024] | off[int,N+1] | ssrc[int,E] | buf[uint2, NB*CAP] |
//   xh[ushort,N*64] | w1t[ushort,4096] | w2t[ushort,4096]
// ---------------------------------------------------------------------------

// Fused setup: block 0 zeroes gcnt, blocks 1-2 transpose+cast weights,
// blocks >=3 cast x -> bf16.
__global__ __launch_bounds__(256) void setup_kernel(const float4* __restrict__ x,
                                                    ushort4* __restrict__ xh, int n4,
                                                    const float* __restrict__ W1,
                                                    const float* __restrict__ W2,
                                                    ushort_t* __restrict__ w1t,
                                                    ushort_t* __restrict__ w2t,
                                                    int* __restrict__ gcnt) {
    int b = blockIdx.x;
    int tid = threadIdx.x;
    if (b == 0) {
#pragma unroll
        for (int i = 0; i < 4; i++) gcnt[tid + 256 * i] = 0;
        return;
    }
    if (b <= 2) {
        const float* W = (b == 1) ? W1 : W2;
        ushort_t* T = (b == 1) ? w1t : w2t;
        for (int i = 0; i < 16; i++) {
            int idx = i * 256 + tid;
            int k = idx >> 6, n = idx & 63;
            T[n * 64 + k] = f2bf(W[idx]);
        }
        return;
    }
    int gid = (b - 3) * 256 + tid;
    if (gid >= n4) return;
    float4 v = x[gid];
    ushort4 o;
    o.x = f2bf(v.x); o.y = f2bf(v.y); o.z = f2bf(v.z); o.w = f2bf(v.w);
    xh[gid] = o;
}

// ---------------------------------------------------------------------------
// Bucket counting-sort (unchanged from R9): coalesced contiguous run writes.
// ---------------------------------------------------------------------------
__global__ __launch_bounds__(256) void bucket_sort_kernel(const int* __restrict__ src,
                                                          const int* __restrict__ dst,
                                                          int* __restrict__ gcnt,
                                                          uint2* __restrict__ buf,
                                                          int nEdges, int nB, int cap) {
    __shared__ uint2 sp[ECHUNK];       // 32 KB sorted pairs
    __shared__ int lhist[NBMAX];
    __shared__ int lofs[NBMAX];
    __shared__ int lbase[NBMAX];
    __shared__ int lcur[NBMAX];
    __shared__ int wsum[4];

    int tid = threadIdx.x;
    int lane = tid & 63;
    int wave = tid >> 6;
    int e0 = blockIdx.x * ECHUNK;
    int cnt = min(ECHUNK, nEdges - e0);

    for (int i = tid; i < nB; i += 256) lhist[i] = 0;
    __syncthreads();

    int es[16], ed[16];
#pragma unroll
    for (int j = 0; j < 16; j++) {
        int ii = tid + j * 256;
        if (ii < cnt) {
            es[j] = src[e0 + ii];
            ed[j] = dst[e0 + ii];
            atomicAdd(&lhist[ed[j] / NPB], 1);
        } else {
            ed[j] = -1;
        }
    }
    __syncthreads();

    int G = (nB + 255) / 256;
    int b0 = tid * G;
    int tsum = 0;
    for (int j = 0; j < G; j++) {
        int b = b0 + j;
        if (b < nB) tsum += lhist[b];
    }
    int incl = tsum;
#pragma unroll
    for (int dd = 1; dd < 64; dd <<= 1) {
        int t2 = __shfl_up(incl, dd, 64);
        if (lane >= dd) incl += t2;
    }
    if (lane == 63) wsum[wave] = incl;
    __syncthreads();
    int wo = 0;
#pragma unroll
    for (int w = 0; w < 4; w++)
        if (w < wave) wo += wsum[w];
    int run = wo + incl - tsum;
    for (int j = 0; j < G; j++) {
        int b = b0 + j;
        if (b < nB) {
            int h = lhist[b];
            lofs[b] = run;
            lcur[b] = run;
            if (h > 0) lbase[b] = atomicAdd(&gcnt[b], h);
            run += h;
        }
    }
    __syncthreads();

#pragma unroll
    for (int j = 0; j < 16; j++) {
        if (ed[j] >= 0) {
            int b = ed[j] / NPB;
            int p = atomicAdd(&lcur[b], 1);
            sp[p] = make_uint2((unsigned)es[j], (unsigned)ed[j]);
        }
    }
    __syncthreads();

    for (int i = tid; i < cnt; i += 256) {
        uint2 pr = sp[i];
        int b = (int)pr.y / NPB;
        int idx = lbase[b] + (i - lofs[b]);
        if (idx < cap) buf[(size_t)b * cap + idx] = pr;
    }
}

// ---------------------------------------------------------------------------
// Per-bucket CSR build (absorbs gscan): block computes its own base by
// reducing gcnt[0..b) (<=1023 ints, L2-resident), then LDS counting-sort by
// exact dst; all global writes contiguous/coalesced.
// ---------------------------------------------------------------------------
__global__ __launch_bounds__(256) void bucket_csr_kernel(const uint2* __restrict__ buf,
                                                         const int* __restrict__ gcnt,
                                                         int* __restrict__ off,
                                                         int* __restrict__ ssrc,
                                                         int nNodes, int nEdges, int cap) {
    __shared__ uint2 spair[CAP];   // 32 KB
    __shared__ int ssort[CAP];     // 16 KB
    __shared__ int hist[NPB];
    __shared__ int lcur[NPB];
    __shared__ int wsum[4];
    __shared__ int redS[4];
    __shared__ int sBase;

    int tid = threadIdx.x;
    int lane = tid & 63;
    int wave = tid >> 6;
    int b = blockIdx.x;
    int lo = b * NPB;
    int cnt = min(gcnt[b], cap);
    const uint2* bp = buf + (size_t)b * cap;

    // base = sum gcnt[0..b)
    int acc = 0;
    for (int i = tid; i < b; i += 256) acc += gcnt[i];
#pragma unroll
    for (int d = 32; d > 0; d >>= 1) acc += __shfl_xor(acc, d, 64);
    if (lane == 0) redS[wave] = acc;
    for (int i = tid; i < NPB; i += 256) hist[i] = 0;
    __syncthreads();
    if (tid == 0) {
        sBase = redS[0] + redS[1] + redS[2] + redS[3];
        if (b == 0) off[nNodes] = nEdges;
    }
    __syncthreads();
    int base = sBase;

    for (int i = tid; i < cnt; i += 256) {
        uint2 pr = bp[i];
        spair[i] = pr;
        atomicAdd(&hist[(int)pr.y - lo], 1);
    }
    __syncthreads();

    // exclusive scan of 192 counts
    int v = (tid < NPB) ? hist[tid] : 0;
    int incl = v;
#pragma unroll
    for (int d = 1; d < 64; d <<= 1) {
        int t = __shfl_up(incl, d, 64);
        if (lane >= d) incl += t;
    }
    if (lane == 63) wsum[wave] = incl;
    __syncthreads();
    int wo = 0;
#pragma unroll
    for (int w = 0; w < 4; w++)
        if (w < wave) wo += wsum[w];
    int excl = wo + incl - v;
    if (tid < NPB) {
        lcur[tid] = excl;
        int g = lo + tid;
        if (g < nNodes) off[g] = base + excl;
    }
    __syncthreads();

    for (int i = tid; i < cnt; i += 256) {
        uint2 pr = spair[i];
        int p = atomicAdd(&lcur[(int)pr.y - lo], 1);
        ssort[p] = (int)pr.x;
    }
    __syncthreads();

    for (int i = tid; i < cnt; i += 256)
        ssrc[base + i] = ssort[i];
}

// ---------------------------------------------------------------------------
// Fused aggregate + MFMA MLP: 64 nodes/block.
// Phase 1 = aggregate_h structure (16 threads/node, fp32 register accumulate)
//           writing bf16 h rows into 9 KB LDS.
// Phase 2 = verified mlp_mfma tile code; wave w owns rows [w*16, w*16+16).
// ---------------------------------------------------------------------------
__global__ __launch_bounds__(256) void agg_mlp_kernel(const ushort_t* __restrict__ xh,
                                                      const int* __restrict__ off,
                                                      const int* __restrict__ ssrc,
                                                      const ushort_t* __restrict__ w1t,
                                                      const ushort_t* __restrict__ w2t,
                                                      const float* __restrict__ b1,
                                                      const float* __restrict__ b2,
                                                      float* __restrict__ out,
                                                      int nNodes) {
    __shared__ ushort_t sh[NPT * HSTR];   // 9216 B

    int tid = threadIdx.x;
    int lane = tid & 63;
    int wave = tid >> 6;
    int quad = lane >> 4;
    int col = lane & 15;
    int base0 = blockIdx.x * NPT;

    // weight fragments + biases
    bf16x8 w1f[4][2], w2f[4][2];
#pragma unroll
    for (int nt = 0; nt < 4; nt++)
#pragma unroll
        for (int ks = 0; ks < 2; ks++) {
            int n = nt * 16 + col;
            w1f[nt][ks] = *(const bf16x8*)(w1t + n * 64 + ks * 32 + quad * 8);
            w2f[nt][ks] = *(const bf16x8*)(w2t + n * 64 + ks * 32 + quad * 8);
        }
    float bb1[4], bb2[4];
#pragma unroll
    for (int nt = 0; nt < 4; nt++) {
        bb1[nt] = b1[nt * 16 + col];
        bb2[nt] = b2[nt * 16 + col];
    }

    // phase 1: each 16-thread group aggregates 4 node rows (grp, grp+16, ...)
    int grp = tid >> 4;
    int f = (tid & 15) * 4;
#pragma unroll
    for (int j = 0; j < NPT / 16; j++) {
        int r = grp + j * 16;
        int n = base0 + r;
        float4 acc = {0.f, 0.f, 0.f, 0.f};
        if (n < nNodes) {
            ushort4 sv = *(const ushort4*)(xh + (size_t)n * D + f);
            acc.x = bf2f(sv.x); acc.y = bf2f(sv.y); acc.z = bf2f(sv.z); acc.w = bf2f(sv.w);
            int e0 = off[n], e1 = off[n + 1];
            for (int e = e0; e < e1; e++) {
                int s = ssrc[e];
                ushort4 v = *(const ushort4*)(xh + (size_t)s * D + f);
                acc.x += bf2f(v.x); acc.y += bf2f(v.y);
                acc.z += bf2f(v.z); acc.w += bf2f(v.w);
            }
        }
        ushort4 o;
        o.x = f2bf(acc.x); o.y = f2bf(acc.y); o.z = f2bf(acc.z); o.w = f2bf(acc.w);
        *(ushort4*)(sh + r * HSTR + f) = o;
    }
    __syncthreads();

    // phase 2: wave owns one 16-row tile
    const ushort_t* rp = sh + (wave * 16 + col) * HSTR;
    bf16x8 a0 = *(const bf16x8*)(rp + quad * 8);
    bf16x8 a1 = *(const bf16x8*)(rp + 32 + quad * 8);

    f32x4 c;
#pragma unroll
    for (int nt = 0; nt < 4; nt++) {
        c = (f32x4){0.f, 0.f, 0.f, 0.f};
        c = __builtin_amdgcn_mfma_f32_16x16x32_bf16(a0, w1f[nt][0], c, 0, 0, 0);
        c = __builtin_amdgcn_mfma_f32_16x16x32_bf16(a1, w1f[nt][1], c, 0, 0, 0);
#pragma unroll
        for (int r = 0; r < 4; r++) {
            float v = fmaxf(c[r] + bb1[nt], 0.0f);
            int m = wave * 16 + quad * 4 + r;
            sh[m * HSTR + nt * 16 + col] = f2bf(v);   // overwrite own tile rows
        }
    }
    // layer-2 A frags (same-wave RAW through LDS; lgkmcnt ordered)
    bf16x8 d0 = *(const bf16x8*)(rp + quad * 8);
    bf16x8 d1 = *(const bf16x8*)(rp + 32 + quad * 8);
#pragma unroll
    for (int nt = 0; nt < 4; nt++) {
        c = (f32x4){0.f, 0.f, 0.f, 0.f};
        c = __builtin_amdgcn_mfma_f32_16x16x32_bf16(d0, w2f[nt][0], c, 0, 0, 0);
        c = __builtin_amdgcn_mfma_f32_16x16x32_bf16(d1, w2f[nt][1], c, 0, 0, 0);
#pragma unroll
        for (int r = 0; r < 4; r++) {
            int g = base0 + wave * 16 + quad * 4 + r;
            if (g < nNodes) out[(size_t)g * D + nt * 16 + col] = c[r] + bb2[nt];
        }
    }
}

// ======================= fallback tier kernels ==============================
__global__ __launch_bounds__(256) void zero_kernel(int* __restrict__ p, int n) {
    int gid = blockIdx.x * 256 + threadIdx.x;
    if (gid < n) p[gid] = 0;
}

__global__ __launch_bounds__(256) void hist_xcd_kernel(const int* __restrict__ dst,
                                                       int* __restrict__ counts,
                                                       int nEdges, int nNodes,
                                                       int blocksPerXcd) {
    int xcd = blockIdx.x % NXCD;
    int slice = blockIdx.x / NXCD;
    int lo = (int)((long long)nNodes * xcd / NXCD);
    int hi = (int)((long long)nNodes * (xcd + 1) / NXCD);
    int per = (nEdges + blocksPerXcd - 1) / blocksPerXcd;
    int e0 = slice * per;
    int e1 = min(e0 + per, nEdges);
    for (int e = e0 + (int)threadIdx.x; e < e1; e += 256) {
        int d = dst[e];
        if (d >= lo && d < hi) atomicAdd(&counts[d], 1);
    }
}

__global__ __launch_bounds__(256) void scan_reduce_kernel(const int* __restrict__ counts,
                                                          int* __restrict__ blockSums,
                                                          int nNodes) {
    __shared__ int ws[4];
    int base = blockIdx.x * SCAN_CHUNK;
    int tid = threadIdx.x;
    int s = 0;
#pragma unroll
    for (int i = 0; i < 4; i++) {
        int idx = base + tid + 256 * i;
        if (idx < nNodes) s += counts[idx];
    }
#pragma unroll
    for (int d = 32; d > 0; d >>= 1) s += __shfl_xor(s, d, 64);
    if ((tid & 63) == 0) ws[tid >> 6] = s;
    __syncthreads();
    if (tid == 0) blockSums[blockIdx.x] = ws[0] + ws[1] + ws[2] + ws[3];
}

__global__ __launch_bounds__(256) void scan_sums_kernel(int* __restrict__ blockSums,
                                                        int* __restrict__ off,
                                                        int nSB, int nNodes, int nEdges) {
    __shared__ int ws[4];
    int tid = threadIdx.x;
    int lane = tid & 63;
    int wave = tid >> 6;
    int v = (tid < nSB) ? blockSums[tid] : 0;
    int incl = v;
#pragma unroll
    for (int d = 1; d < 64; d <<= 1) {
        int t = __shfl_up(incl, d, 64);
        if (lane >= d) incl += t;
    }
    if (lane == 63) ws[wave] = incl;
    __syncthreads();
    int waveOff = 0;
#pragma unroll
    for (int w = 0; w < 4; w++)
        if (w < wave) waveOff += ws[w];
    if (tid < nSB) blockSums[tid] = waveOff + incl - v;
    if (tid == 0) off[nNodes] = nEdges;
}

__global__ __launch_bounds__(1024) void scan_write_kernel(int* __restrict__ off,
                                                          int* __restrict__ cur,
                                                          const int* __restrict__ blockSums,
                                                          int nNodes) {
    __shared__ int waveSums[16];
    int tid = threadIdx.x;
    int lane = tid & 63;
    int wave = tid >> 6;
    int i = blockIdx.x * SCAN_CHUNK + tid;
    int v = (i < nNodes) ? off[i] : 0;
    int incl = v;
#pragma unroll
    for (int d = 1; d < 64; d <<= 1) {
        int t = __shfl_up(incl, d, 64);
        if (lane >= d) incl += t;
    }
    if (lane == 63) waveSums[wave] = incl;
    __syncthreads();
    if (wave == 0) {
        int wv = (lane < 16) ? waveSums[lane] : 0;
        int s = wv;
#pragma unroll
        for (int d = 1; d < 16; d <<= 1) {
            int t = __shfl_up(s, d, 64);
            if (lane >= d) s += t;
        }
        if (lane < 16) waveSums[lane] = s - wv;
    }
    __syncthreads();
    if (i < nNodes) {
        int excl = blockSums[blockIdx.x] + waveSums[wave] + incl - v;
        off[i] = excl;
        cur[i] = excl;
    }
}

__global__ __launch_bounds__(256) void fill_xcd_kernel(const int* __restrict__ src,
                                                       const int* __restrict__ dst,
                                                       int* __restrict__ cur,
                                                       int* __restrict__ ssrc,
                                                       int nEdges, int nNodes,
                                                       int blocksPerXcd) {
    int xcd = blockIdx.x % NXCD;
    int slice = blockIdx.x / NXCD;
    int lo = (int)((long long)nNodes * xcd / NXCD);
    int hi = (int)((long long)nNodes * (xcd + 1) / NXCD);
    int per = (nEdges + blocksPerXcd - 1) / blocksPerXcd;
    int e0 = slice * per;
    int e1 = min(e0 + per, nEdges);
    for (int e = e0 + (int)threadIdx.x; e < e1; e += 256) {
        int d = dst[e];
        if (d >= lo && d < hi) {
            int p = atomicAdd(&cur[d], 1);
            ssrc[p] = src[e];
        }
    }
}

__global__ __launch_bounds__(256) void aggregate_kernel(const float* __restrict__ x,
                                                        const int* __restrict__ off,
                                                        const int* __restrict__ ssrc,
                                                        float* __restrict__ out,
                                                        int nNodes) {
    int gid = blockIdx.x * 256 + threadIdx.x;
    int n = gid >> 4;
    if (n >= nNodes) return;
    int f = (gid & 15) * 4;
    float4 acc = *(const float4*)(x + (size_t)n * D + f);
    int e0 = off[n], e1 = off[n + 1];
    for (int e = e0; e < e1; e++) {
        int s = ssrc[e];
        float4 v = *(const float4*)(x + (size_t)s * D + f);
        acc.x += v.x; acc.y += v.y; acc.z += v.z; acc.w += v.w;
    }
    *(float4*)(out + (size_t)n * D + f) = acc;
}

__global__ __launch_bounds__(256) void mlp_reg_kernel(const float* hin,
                                                      const float* __restrict__ W1,
                                                      const float* __restrict__ b1,
                                                      const float* __restrict__ W2,
                                                      const float* __restrict__ b2,
                                                      float* out,
                                                      int nNodes) {
    int lane = threadIdx.x & 63;
    int wave = threadIdx.x >> 6;
    float w1[D], w2[D];
#pragma unroll
    for (int k = 0; k < D; k++) w1[k] = W1[k * D + lane];
#pragma unroll
    for (int k = 0; k < D; k++) w2[k] = W2[k * D + lane];
    float bb1 = b1[lane];
    float bb2 = b2[lane];
    int gw = blockIdx.x * 4 + wave;
    int nW = gridDim.x * 4;
    for (int n = gw; n < nNodes; n += nW) {
        float hv = hin[(size_t)n * D + lane];
        float a0 = bb1, a1 = 0.0f, a2 = 0.0f, a3 = 0.0f;
#pragma unroll
        for (int k = 0; k < D; k += 4) {
            float h0 = __uint_as_float(__builtin_amdgcn_readlane(__float_as_uint(hv), k + 0));
            float h1 = __uint_as_float(__builtin_amdgcn_readlane(__float_as_uint(hv), k + 1));
            float h2 = __uint_as_float(__builtin_amdgcn_readlane(__float_as_uint(hv), k + 2));
            float h3 = __uint_as_float(__builtin_amdgcn_readlane(__float_as_uint(hv), k + 3));
            a0 = fmaf(h0, w1[k + 0], a0);
            a1 = fmaf(h1, w1[k + 1], a1);
            a2 = fmaf(h2, w1[k + 2], a2);
            a3 = fmaf(h3, w1[k + 3], a3);
        }
        float m = fmaxf((a0 + a1) + (a2 + a3), 0.0f);
        float c0 = bb2, c1 = 0.0f, c2 = 0.0f, c3 = 0.0f;
#pragma unroll
        for (int k = 0; k < D; k += 4) {
            float h0 = __uint_as_float(__builtin_amdgcn_readlane(__float_as_uint(m), k + 0));
            float h1 = __uint_as_float(__builtin_amdgcn_readlane(__float_as_uint(m), k + 1));
            float h2 = __uint_as_float(__builtin_amdgcn_readlane(__float_as_uint(m), k + 2));
            float h3 = __uint_as_float(__builtin_amdgcn_readlane(__float_as_uint(m), k + 3));
            c0 = fmaf(h0, w2[k + 0], c0);
            c1 = fmaf(h1, w2[k + 1], c1);
            c2 = fmaf(h2, w2[k + 2], c2);
            c3 = fmaf(h3, w2[k + 3], c3);
        }
        out[(size_t)n * D + lane] = (c0 + c1) + (c2 + c3);
    }
}

extern "C" void kernel_launch(void* const* d_in, const int* in_sizes, int n_in,
                              void* d_out, int out_size, void* d_ws, size_t ws_size,
                              hipStream_t stream) {
    const float* x  = (const float*)d_in[0];
    const int*   ei = (const int*)d_in[1];
    const float* W1 = (const float*)d_in[2];
    const float* b1 = (const float*)d_in[3];
    const float* W2 = (const float*)d_in[4];
    const float* b2 = (const float*)d_in[5];
    float* out = (float*)d_out;

    const int nNodes = in_sizes[0] / D;
    const int nEdges = in_sizes[1] / 2;
    const int* src = ei;
    const int* dst = ei + nEdges;

    const int NB = (nNodes + NPB - 1) / NPB;

    // ---- tier 0 layout ----
    int* gcnt = (int*)d_ws;                                 // 1024
    int* off  = gcnt + 1024;                                // N+1
    int* ssrc = off + (nNodes + 1);                         // E
    uint2* buf = (uint2*)(ssrc + nEdges);                   // NB*CAP
    ushort_t* xh  = (ushort_t*)(buf + (size_t)NB * CAP);    // N*64
    ushort_t* w1t = xh + (size_t)nNodes * D;                // 4096
    ushort_t* w2t = w1t + 4096;                             // 4096

    size_t wsT0 = (size_t)(1024 + nNodes + 1 + nEdges) * 4
                + (size_t)NB * CAP * 8
                + (size_t)nNodes * D * 2 + 2 * 4096 * 2;
    bool tier0 = (ws_size >= wsT0) && (NB <= NBMAX)
              && ((long long)nEdges * NPB / (nNodes > 0 ? nNodes : 1) * 14 / 10 < CAP);

    if (tier0) {
        int n4 = nNodes * (D / 4);
        setup_kernel<<<3 + (n4 + 255) / 256, 256, 0, stream>>>(
            (const float4*)x, (ushort4*)xh, n4, W1, W2, w1t, w2t, gcnt);
        bucket_sort_kernel<<<(nEdges + ECHUNK - 1) / ECHUNK, 256, 0, stream>>>(
            src, dst, gcnt, buf, nEdges, NB, CAP);
        bucket_csr_kernel<<<NB, 256, 0, stream>>>(
            buf, gcnt, off, ssrc, nNodes, nEdges, CAP);
        agg_mlp_kernel<<<(nNodes + NPT - 1) / NPT, 256, 0, stream>>>(
            xh, off, ssrc, w1t, w2t, b1, b2, out, nNodes);
        return;
    }

    // ---- fallback: sweep pipeline (fp32 CSR + vector-ALU MLP) ----
    const int nSB = (nNodes + SCAN_CHUNK - 1) / SCAN_CHUNK;
    int* foff  = (int*)d_ws;
    int* fcur  = foff + (nNodes + 1);
    int* fssrc = fcur + nNodes;
    int* fsums = fssrc + nEdges;

    zero_kernel<<<(nNodes + 1 + 255) / 256, 256, 0, stream>>>(foff, nNodes + 1);
    {
        const int blocksPerXcd = 256;
        hist_xcd_kernel<<<blocksPerXcd * NXCD, 256, 0, stream>>>(
            dst, foff, nEdges, nNodes, blocksPerXcd);
    }
    scan_reduce_kernel<<<nSB, 256, 0, stream>>>(foff, fsums, nNodes);
    scan_sums_kernel<<<1, 256, 0, stream>>>(fsums, foff, nSB, nNodes, nEdges);
    scan_write_kernel<<<nSB, 1024, 0, stream>>>(foff, fcur, fsums, nNodes);
    {
        const int blocksPerXcd = 256;
        fill_xcd_kernel<<<blocksPerXcd * NXCD, 256, 0, stream>>>(
            src, dst, fcur, fssrc, nEdges, nNodes, blocksPerXcd);
    }
    long long work = (long long)nNodes * 16;
    aggregate_kernel<<<(int)((work + 255) / 256), 256, 0, stream>>>(x, foff, fssrc, out, nNodes);
    mlp_reg_kernel<<<6250, 256, 0, stream>>>(out, W1, b1, W2, b2, out, nNodes);
}

// Round 12
// 183.581 us; speedup vs baseline: 1.2565x; 1.2565x over previous
//
#include <hip/hip_runtime.h>

#define D 64
#define SCAN_CHUNK 1024
#define NXCD 8
#define NPB 192          // nodes per bucket (CSR build)
#define NBMAX 1024       // max buckets for tier-0
#define CAP 4096         // bucket capacity (mean 2400 here; 34 sigma headroom)
#define ECHUNK 4096      // edges per bucket_sort block
#define HSTR 72          // LDS row stride (ushorts)

typedef unsigned short ushort_t;
typedef __bf16 bf16_t;
typedef __bf16 bf16x8 __attribute__((ext_vector_type(8)));
typedef float f32x4 __attribute__((ext_vector_type(4)));

__device__ __forceinline__ ushort_t f2bf(float v) {
    unsigned u = __float_as_uint(v);
    return (ushort_t)((u + 0x7FFF + ((u >> 16) & 1)) >> 16);
}
__device__ __forceinline__ float bf2f(ushort_t h) {
    return __uint_as_float((unsigned)h << 16);
}

// ---------------------------------------------------------------------------
// d_ws layout (tier 0):
//   gcnt[int,1024] | off[int,N+1] | ssrc[int,E] | buf[uint2, NB*CAP] |
//   xh[ushort,N*64] | hb[ushort,N*64](aliases buf) | w1t | w2t
// ---------------------------------------------------------------------------

// Fused setup: block 0 zeroes gcnt, blocks 1-2 transpose+cast weights,
// blocks >=3 cast x -> bf16.
__global__ __launch_bounds__(256) void setup_kernel(const float4* __restrict__ x,
                                                    ushort4* __restrict__ xh, int n4,
                                                    const float* __restrict__ W1,
                                                    const float* __restrict__ W2,
                                                    ushort_t* __restrict__ w1t,
                                                    ushort_t* __restrict__ w2t,
                                                    int* __restrict__ gcnt) {
    int b = blockIdx.x;
    int tid = threadIdx.x;
    if (b == 0) {
#pragma unroll
        for (int i = 0; i < 4; i++) gcnt[tid + 256 * i] = 0;
        return;
    }
    if (b <= 2) {
        const float* W = (b == 1) ? W1 : W2;
        ushort_t* T = (b == 1) ? w1t : w2t;
        for (int i = 0; i < 16; i++) {
            int idx = i * 256 + tid;
            int k = idx >> 6, n = idx & 63;
            T[n * 64 + k] = f2bf(W[idx]);
        }
        return;
    }
    int gid = (b - 3) * 256 + tid;
    if (gid >= n4) return;
    float4 v = x[gid];
    ushort4 o;
    o.x = f2bf(v.x); o.y = f2bf(v.y); o.z = f2bf(v.z); o.w = f2bf(v.w);
    xh[gid] = o;
}

// ---------------------------------------------------------------------------
// Bucket counting-sort: coalesced contiguous run writes (R9-proven).
// ---------------------------------------------------------------------------
__global__ __launch_bounds__(256) void bucket_sort_kernel(const int* __restrict__ src,
                                                          const int* __restrict__ dst,
                                                          int* __restrict__ gcnt,
                                                          uint2* __restrict__ buf,
                                                          int nEdges, int nB, int cap) {
    __shared__ uint2 sp[ECHUNK];       // 32 KB sorted pairs
    __shared__ int lhist[NBMAX];
    __shared__ int lofs[NBMAX];
    __shared__ int lbase[NBMAX];
    __shared__ int lcur[NBMAX];
    __shared__ int wsum[4];

    int tid = threadIdx.x;
    int lane = tid & 63;
    int wave = tid >> 6;
    int e0 = blockIdx.x * ECHUNK;
    int cnt = min(ECHUNK, nEdges - e0);

    for (int i = tid; i < nB; i += 256) lhist[i] = 0;
    __syncthreads();

    int es[16], ed[16];
#pragma unroll
    for (int j = 0; j < 16; j++) {
        int ii = tid + j * 256;
        if (ii < cnt) {
            es[j] = src[e0 + ii];
            ed[j] = dst[e0 + ii];
            atomicAdd(&lhist[ed[j] / NPB], 1);
        } else {
            ed[j] = -1;
        }
    }
    __syncthreads();

    int G = (nB + 255) / 256;
    int b0 = tid * G;
    int tsum = 0;
    for (int j = 0; j < G; j++) {
        int b = b0 + j;
        if (b < nB) tsum += lhist[b];
    }
    int incl = tsum;
#pragma unroll
    for (int dd = 1; dd < 64; dd <<= 1) {
        int t2 = __shfl_up(incl, dd, 64);
        if (lane >= dd) incl += t2;
    }
    if (lane == 63) wsum[wave] = incl;
    __syncthreads();
    int wo = 0;
#pragma unroll
    for (int w = 0; w < 4; w++)
        if (w < wave) wo += wsum[w];
    int run = wo + incl - tsum;
    for (int j = 0; j < G; j++) {
        int b = b0 + j;
        if (b < nB) {
            int h = lhist[b];
            lofs[b] = run;
            lcur[b] = run;
            if (h > 0) lbase[b] = atomicAdd(&gcnt[b], h);
            run += h;
        }
    }
    __syncthreads();

#pragma unroll
    for (int j = 0; j < 16; j++) {
        if (ed[j] >= 0) {
            int b = ed[j] / NPB;
            int p = atomicAdd(&lcur[b], 1);
            sp[p] = make_uint2((unsigned)es[j], (unsigned)ed[j]);
        }
    }
    __syncthreads();

    for (int i = tid; i < cnt; i += 256) {
        uint2 pr = sp[i];
        int b = (int)pr.y / NPB;
        int idx = lbase[b] + (i - lofs[b]);
        if (idx < cap) buf[(size_t)b * cap + idx] = pr;
    }
}

// ---------------------------------------------------------------------------
// Per-bucket CSR build (absorbs gscan; R10/R11-proven).
// ---------------------------------------------------------------------------
__global__ __launch_bounds__(256) void bucket_csr_kernel(const uint2* __restrict__ buf,
                                                         const int* __restrict__ gcnt,
                                                         int* __restrict__ off,
                                                         int* __restrict__ ssrc,
                                                         int nNodes, int nEdges, int cap) {
    __shared__ uint2 spair[CAP];   // 32 KB
    __shared__ int ssort[CAP];     // 16 KB
    __shared__ int hist[NPB];
    __shared__ int lcur[NPB];
    __shared__ int wsum[4];
    __shared__ int redS[4];
    __shared__ int sBase;

    int tid = threadIdx.x;
    int lane = tid & 63;
    int wave = tid >> 6;
    int b = blockIdx.x;
    int lo = b * NPB;
    int cnt = min(gcnt[b], cap);
    const uint2* bp = buf + (size_t)b * cap;

    int acc = 0;
    for (int i = tid; i < b; i += 256) acc += gcnt[i];
#pragma unroll
    for (int d = 32; d > 0; d >>= 1) acc += __shfl_xor(acc, d, 64);
    if (lane == 0) redS[wave] = acc;
    for (int i = tid; i < NPB; i += 256) hist[i] = 0;
    __syncthreads();
    if (tid == 0) {
        sBase = redS[0] + redS[1] + redS[2] + redS[3];
        if (b == 0) off[nNodes] = nEdges;
    }
    __syncthreads();
    int base = sBase;

    for (int i = tid; i < cnt; i += 256) {
        uint2 pr = bp[i];
        spair[i] = pr;
        atomicAdd(&hist[(int)pr.y - lo], 1);
    }
    __syncthreads();

    int v = (tid < NPB) ? hist[tid] : 0;
    int incl = v;
#pragma unroll
    for (int d = 1; d < 64; d <<= 1) {
        int t = __shfl_up(incl, d, 64);
        if (lane >= d) incl += t;
    }
    if (lane == 63) wsum[wave] = incl;
    __syncthreads();
    int wo = 0;
#pragma unroll
    for (int w = 0; w < 4; w++)
        if (w < wave) wo += wsum[w];
    int excl = wo + incl - v;
    if (tid < NPB) {
        lcur[tid] = excl;
        int g = lo + tid;
        if (g < nNodes) off[g] = base + excl;
    }
    __syncthreads();

    for (int i = tid; i < cnt; i += 256) {
        uint2 pr = spair[i];
        int p = atomicAdd(&lcur[(int)pr.y - lo], 1);
        ssort[p] = (int)pr.x;
    }
    __syncthreads();

    for (int i = tid; i < cnt; i += 256)
        ssrc[base + i] = ssort[i];
}

// ---------------------------------------------------------------------------
// Aggregate -> bf16 h: hb[n] = bf16( xh[n] + sum xh[ssrc[e]] )
// 16 threads/node (R10-proven granularity), edge loop unrolled x4 so four
// independent row gathers are in flight per group (attacks the 2-deep
// dependent-load latency chain seen in R10's 2.57 TB/s plateau).
// ---------------------------------------------------------------------------
__global__ __launch_bounds__(256) void aggregate_h_kernel(const ushort_t* __restrict__ xh,
                                                          const int* __restrict__ off,
                                                          const int* __restrict__ ssrc,
                                                          ushort_t* __restrict__ hb,
                                                          int nNodes) {
    int gid = blockIdx.x * 256 + threadIdx.x;
    int n = gid >> 4;
    if (n >= nNodes) return;
    int f = (gid & 15) * 4;
    ushort4 sv = *(const ushort4*)(xh + (size_t)n * D + f);
    float4 acc;
    acc.x = bf2f(sv.x); acc.y = bf2f(sv.y); acc.z = bf2f(sv.z); acc.w = bf2f(sv.w);
    int e0 = off[n], e1 = off[n + 1];
    int e = e0;
    for (; e + 4 <= e1; e += 4) {
        int s0 = ssrc[e + 0];
        int s1 = ssrc[e + 1];
        int s2 = ssrc[e + 2];
        int s3 = ssrc[e + 3];
        ushort4 v0 = *(const ushort4*)(xh + (size_t)s0 * D + f);
        ushort4 v1 = *(const ushort4*)(xh + (size_t)s1 * D + f);
        ushort4 v2 = *(const ushort4*)(xh + (size_t)s2 * D + f);
        ushort4 v3 = *(const ushort4*)(xh + (size_t)s3 * D + f);
        acc.x += bf2f(v0.x) + bf2f(v1.x) + bf2f(v2.x) + bf2f(v3.x);
        acc.y += bf2f(v0.y) + bf2f(v1.y) + bf2f(v2.y) + bf2f(v3.y);
        acc.z += bf2f(v0.z) + bf2f(v1.z) + bf2f(v2.z) + bf2f(v3.z);
        acc.w += bf2f(v0.w) + bf2f(v1.w) + bf2f(v2.w) + bf2f(v3.w);
    }
    for (; e < e1; e++) {
        int s = ssrc[e];
        ushort4 v = *(const ushort4*)(xh + (size_t)s * D + f);
        acc.x += bf2f(v.x); acc.y += bf2f(v.y); acc.z += bf2f(v.z); acc.w += bf2f(v.w);
    }
    ushort4 o;
    o.x = f2bf(acc.x); o.y = f2bf(acc.y); o.z = f2bf(acc.z); o.w = f2bf(acc.w);
    *(ushort4*)(hb + (size_t)n * D + f) = o;
}

// ---------------------------------------------------------------------------
// MFMA MLP: one wave per 16-node tile (R6-R10 proven).
// ---------------------------------------------------------------------------
__global__ __launch_bounds__(256) void mlp_mfma_kernel(const ushort_t* __restrict__ hb,
                                                       const ushort_t* __restrict__ w1t,
                                                       const ushort_t* __restrict__ w2t,
                                                       const float* __restrict__ b1,
                                                       const float* __restrict__ b2,
                                                       float* __restrict__ out,
                                                       int nNodes, int nTiles) {
    __shared__ ushort_t sh[4][16 * HSTR];
    int lane = threadIdx.x & 63;
    int wave = threadIdx.x >> 6;
    int quad = lane >> 4;
    int col = lane & 15;

    bf16x8 w1f[4][2], w2f[4][2];
#pragma unroll
    for (int nt = 0; nt < 4; nt++)
#pragma unroll
        for (int ks = 0; ks < 2; ks++) {
            int n = nt * 16 + col;
            w1f[nt][ks] = *(const bf16x8*)(w1t + n * 64 + ks * 32 + quad * 8);
            w2f[nt][ks] = *(const bf16x8*)(w2t + n * 64 + ks * 32 + quad * 8);
        }
    float bb1[4], bb2[4];
#pragma unroll
    for (int nt = 0; nt < 4; nt++) {
        bb1[nt] = b1[nt * 16 + col];
        bb2[nt] = b2[nt * 16 + col];
    }

    ushort_t* sw = sh[wave];
    int gw = blockIdx.x * 4 + wave;
    int nW = gridDim.x * 4;
    for (int tile = gw; tile < nTiles; tile += nW) {
        int base = tile * 16;
        int arow = min(base + col, nNodes - 1);
        const ushort_t* hp = hb + (size_t)arow * D;
        bf16x8 a0 = *(const bf16x8*)(hp + quad * 8);
        bf16x8 a1 = *(const bf16x8*)(hp + 32 + quad * 8);

        f32x4 c;
#pragma unroll
        for (int nt = 0; nt < 4; nt++) {
            c = (f32x4){0.f, 0.f, 0.f, 0.f};
            c = __builtin_amdgcn_mfma_f32_16x16x32_bf16(a0, w1f[nt][0], c, 0, 0, 0);
            c = __builtin_amdgcn_mfma_f32_16x16x32_bf16(a1, w1f[nt][1], c, 0, 0, 0);
#pragma unroll
            for (int r = 0; r < 4; r++) {
                float v = fmaxf(c[r] + bb1[nt], 0.0f);
                int m = quad * 4 + r;
                sw[m * HSTR + nt * 16 + col] = f2bf(v);
            }
        }
        bf16x8 d0 = *(const bf16x8*)(sw + col * HSTR + quad * 8);
        bf16x8 d1 = *(const bf16x8*)(sw + col * HSTR + 32 + quad * 8);
#pragma unroll
        for (int nt = 0; nt < 4; nt++) {
            c = (f32x4){0.f, 0.f, 0.f, 0.f};
            c = __builtin_amdgcn_mfma_f32_16x16x32_bf16(d0, w2f[nt][0], c, 0, 0, 0);
            c = __builtin_amdgcn_mfma_f32_16x16x32_bf16(d1, w2f[nt][1], c, 0, 0, 0);
#pragma unroll
            for (int r = 0; r < 4; r++) {
                int row = base + quad * 4 + r;
                if (row < nNodes) out[(size_t)row * D + nt * 16 + col] = c[r] + bb2[nt];
            }
        }
    }
}

// ======================= fallback tier kernels ==============================
__global__ __launch_bounds__(256) void zero_kernel(int* __restrict__ p, int n) {
    int gid = blockIdx.x * 256 + threadIdx.x;
    if (gid < n) p[gid] = 0;
}

__global__ __launch_bounds__(256) void hist_xcd_kernel(const int* __restrict__ dst,
                                                       int* __restrict__ counts,
                                                       int nEdges, int nNodes,
                                                       int blocksPerXcd) {
    int xcd = blockIdx.x % NXCD;
    int slice = blockIdx.x / NXCD;
    int lo = (int)((long long)nNodes * xcd / NXCD);
    int hi = (int)((long long)nNodes * (xcd + 1) / NXCD);
    int per = (nEdges + blocksPerXcd - 1) / blocksPerXcd;
    int e0 = slice * per;
    int e1 = min(e0 + per, nEdges);
    for (int e = e0 + (int)threadIdx.x; e < e1; e += 256) {
        int d = dst[e];
        if (d >= lo && d < hi) atomicAdd(&counts[d], 1);
    }
}

__global__ __launch_bounds__(256) void scan_reduce_kernel(const int* __restrict__ counts,
                                                          int* __restrict__ blockSums,
                                                          int nNodes) {
    __shared__ int ws[4];
    int base = blockIdx.x * SCAN_CHUNK;
    int tid = threadIdx.x;
    int s = 0;
#pragma unroll
    for (int i = 0; i < 4; i++) {
        int idx = base + tid + 256 * i;
        if (idx < nNodes) s += counts[idx];
    }
#pragma unroll
    for (int d = 32; d > 0; d >>= 1) s += __shfl_xor(s, d, 64);
    if ((tid & 63) == 0) ws[tid >> 6] = s;
    __syncthreads();
    if (tid == 0) blockSums[blockIdx.x] = ws[0] + ws[1] + ws[2] + ws[3];
}

__global__ __launch_bounds__(256) void scan_sums_kernel(int* __restrict__ blockSums,
                                                        int* __restrict__ off,
                                                        int nSB, int nNodes, int nEdges) {
    __shared__ int ws[4];
    int tid = threadIdx.x;
    int lane = tid & 63;
    int wave = tid >> 6;
    int v = (tid < nSB) ? blockSums[tid] : 0;
    int incl = v;
#pragma unroll
    for (int d = 1; d < 64; d <<= 1) {
        int t = __shfl_up(incl, d, 64);
        if (lane >= d) incl += t;
    }
    if (lane == 63) ws[wave] = incl;
    __syncthreads();
    int waveOff = 0;
#pragma unroll
    for (int w = 0; w < 4; w++)
        if (w < wave) waveOff += ws[w];
    if (tid < nSB) blockSums[tid] = waveOff + incl - v;
    if (tid == 0) off[nNodes] = nEdges;
}

__global__ __launch_bounds__(1024) void scan_write_kernel(int* __restrict__ off,
                                                          int* __restrict__ cur,
                                                          const int* __restrict__ blockSums,
                                                          int nNodes) {
    __shared__ int waveSums[16];
    int tid = threadIdx.x;
    int lane = tid & 63;
    int wave = tid >> 6;
    int i = blockIdx.x * SCAN_CHUNK + tid;
    int v = (i < nNodes) ? off[i] : 0;
    int incl = v;
#pragma unroll
    for (int d = 1; d < 64; d <<= 1) {
        int t = __shfl_up(incl, d, 64);
        if (lane >= d) incl += t;
    }
    if (lane == 63) waveSums[wave] = incl;
    __syncthreads();
    if (wave == 0) {
        int wv = (lane < 16) ? waveSums[lane] : 0;
        int s = wv;
#pragma unroll
        for (int d = 1; d < 16; d <<= 1) {
            int t = __shfl_up(s, d, 64);
            if (lane >= d) s += t;
        }
        if (lane < 16) waveSums[lane] = s - wv;
    }
    __syncthreads();
    if (i < nNodes) {
        int excl = blockSums[blockIdx.x] + waveSums[wave] + incl - v;
        off[i] = excl;
        cur[i] = excl;
    }
}

__global__ __launch_bounds__(256) void fill_xcd_kernel(const int* __restrict__ src,
                                                       const int* __restrict__ dst,
                                                       int* __restrict__ cur,
                                                       int* __restrict__ ssrc,
                                                       int nEdges, int nNodes,
                                                       int blocksPerXcd) {
    int xcd = blockIdx.x % NXCD;
    int slice = blockIdx.x / NXCD;
    int lo = (int)((long long)nNodes * xcd / NXCD);
    int hi = (int)((long long)nNodes * (xcd + 1) / NXCD);
    int per = (nEdges + blocksPerXcd - 1) / blocksPerXcd;
    int e0 = slice * per;
    int e1 = min(e0 + per, nEdges);
    for (int e = e0 + (int)threadIdx.x; e < e1; e += 256) {
        int d = dst[e];
        if (d >= lo && d < hi) {
            int p = atomicAdd(&cur[d], 1);
            ssrc[p] = src[e];
        }
    }
}

__global__ __launch_bounds__(256) void aggregate_kernel(const float* __restrict__ x,
                                                        const int* __restrict__ off,
                                                        const int* __restrict__ ssrc,
                                                        float* __restrict__ out,
                                                        int nNodes) {
    int gid = blockIdx.x * 256 + threadIdx.x;
    int n = gid >> 4;
    if (n >= nNodes) return;
    int f = (gid & 15) * 4;
    float4 acc = *(const float4*)(x + (size_t)n * D + f);
    int e0 = off[n], e1 = off[n + 1];
    for (int e = e0; e < e1; e++) {
        int s = ssrc[e];
        float4 v = *(const float4*)(x + (size_t)s * D + f);
        acc.x += v.x; acc.y += v.y; acc.z += v.z; acc.w += v.w;
    }
    *(float4*)(out + (size_t)n * D + f) = acc;
}

__global__ __launch_bounds__(256) void mlp_reg_kernel(const float* hin,
                                                      const float* __restrict__ W1,
                                                      const float* __restrict__ b1,
                                                      const float* __restrict__ W2,
                                                      const float* __restrict__ b2,
                                                      float* out,
                                                      int nNodes) {
    int lane = threadIdx.x & 63;
    int wave = threadIdx.x >> 6;
    float w1[D], w2[D];
#pragma unroll
    for (int k = 0; k < D; k++) w1[k] = W1[k * D + lane];
#pragma unroll
    for (int k = 0; k < D; k++) w2[k] = W2[k * D + lane];
    float bb1 = b1[lane];
    float bb2 = b2[lane];
    int gw = blockIdx.x * 4 + wave;
    int nW = gridDim.x * 4;
    for (int n = gw; n < nNodes; n += nW) {
        float hv = hin[(size_t)n * D + lane];
        float a0 = bb1, a1 = 0.0f, a2 = 0.0f, a3 = 0.0f;
#pragma unroll
        for (int k = 0; k < D; k += 4) {
            float h0 = __uint_as_float(__builtin_amdgcn_readlane(__float_as_uint(hv), k + 0));
            float h1 = __uint_as_float(__builtin_amdgcn_readlane(__float_as_uint(hv), k + 1));
            float h2 = __uint_as_float(__builtin_amdgcn_readlane(__float_as_uint(hv), k + 2));
            float h3 = __uint_as_float(__builtin_amdgcn_readlane(__float_as_uint(hv), k + 3));
            a0 = fmaf(h0, w1[k + 0], a0);
            a1 = fmaf(h1, w1[k + 1], a1);
            a2 = fmaf(h2, w1[k + 2], a2);
            a3 = fmaf(h3, w1[k + 3], a3);
        }
        float m = fmaxf((a0 + a1) + (a2 + a3), 0.0f);
        float c0 = bb2, c1 = 0.0f, c2 = 0.0f, c3 = 0.0f;
#pragma unroll
        for (int k = 0; k < D; k += 4) {
            float h0 = __uint_as_float(__builtin_amdgcn_readlane(__float_as_uint(m), k + 0));
            float h1 = __uint_as_float(__builtin_amdgcn_readlane(__float_as_uint(m), k + 1));
            float h2 = __uint_as_float(__builtin_amdgcn_readlane(__float_as_uint(m), k + 2));
            float h3 = __uint_as_float(__builtin_amdgcn_readlane(__float_as_uint(m), k + 3));
            c0 = fmaf(h0, w2[k + 0], c0);
            c1 = fmaf(h1, w2[k + 1], c1);
            c2 = fmaf(h2, w2[k + 2], c2);
            c3 = fmaf(h3, w2[k + 3], c3);
        }
        out[(size_t)n * D + lane] = (c0 + c1) + (c2 + c3);
    }
}

extern "C" void kernel_launch(void* const* d_in, const int* in_sizes, int n_in,
                              void* d_out, int out_size, void* d_ws, size_t ws_size,
                              hipStream_t stream) {
    const float* x  = (const float*)d_in[0];
    const int*   ei = (const int*)d_in[1];
    const float* W1 = (const float*)d_in[2];
    const float* b1 = (const float*)d_in[3];
    const float* W2 = (const float*)d_in[4];
    const float* b2 = (const float*)d_in[5];
    float* out = (float*)d_out;

    const int nNodes = in_sizes[0] / D;
    const int nEdges = in_sizes[1] / 2;
    const int* src = ei;
    const int* dst = ei + nEdges;

    const int NB = (nNodes + NPB - 1) / NPB;

    // ---- tier 0 layout ----
    int* gcnt = (int*)d_ws;                                 // 1024
    int* off  = gcnt + 1024;                                // N+1
    int* ssrc = off + (nNodes + 1);                         // E
    uint2* buf = (uint2*)(ssrc + nEdges);                   // NB*CAP
    ushort_t* xh  = (ushort_t*)(buf + (size_t)NB * CAP);    // N*64
    ushort_t* w1t = xh + (size_t)nNodes * D;                // 4096
    ushort_t* w2t = w1t + 4096;                             // 4096

    size_t wsT0 = (size_t)(1024 + nNodes + 1 + nEdges) * 4
                + (size_t)NB * CAP * 8
                + (size_t)nNodes * D * 2 + 2 * 4096 * 2;
    bool tier0 = (ws_size >= wsT0) && (NB <= NBMAX)
              && ((long long)nEdges * NPB / (nNodes > 0 ? nNodes : 1) * 14 / 10 < CAP)
              && ((size_t)NB * CAP * 8 >= (size_t)nNodes * D * 2);  // hb aliases buf

    if (tier0) {
        int n4 = nNodes * (D / 4);
        setup_kernel<<<3 + (n4 + 255) / 256, 256, 0, stream>>>(
            (const float4*)x, (ushort4*)xh, n4, W1, W2, w1t, w2t, gcnt);
        bucket_sort_kernel<<<(nEdges + ECHUNK - 1) / ECHUNK, 256, 0, stream>>>(
            src, dst, gcnt, buf, nEdges, NB, CAP);
        bucket_csr_kernel<<<NB, 256, 0, stream>>>(
            buf, gcnt, off, ssrc, nNodes, nEdges, CAP);
        // buf is dead after bucket_csr; reuse it for the bf16 h buffer
        ushort_t* hb = (ushort_t*)buf;
        long long work = (long long)nNodes * 16;
        aggregate_h_kernel<<<(int)((work + 255) / 256), 256, 0, stream>>>(
            xh, off, ssrc, hb, nNodes);
        int nTiles = (nNodes + 15) / 16;
        mlp_mfma_kernel<<<(nTiles + 3) / 4, 256, 0, stream>>>(
            hb, w1t, w2t, b1, b2, out, nNodes, nTiles);
        return;
    }

    // ---- fallback: sweep pipeline (fp32 CSR + vector-ALU MLP) ----
    const int nSB = (nNodes + SCAN_CHUNK - 1) / SCAN_CHUNK;
    int* foff  = (int*)d_ws;
    int* fcur  = foff + (nNodes + 1);
    int* fssrc = fcur + nNodes;
    int* fsums = fssrc + nEdges;

    zero_kernel<<<(nNodes + 1 + 255) / 256, 256, 0, stream>>>(foff, nNodes + 1);
    {
        const int blocksPerXcd = 256;
        hist_xcd_kernel<<<blocksPerXcd * NXCD, 256, 0, stream>>>(
            dst, foff, nEdges, nNodes, blocksPerXcd);
    }
    scan_reduce_kernel<<<nSB, 256, 0, stream>>>(foff, fsums, nNodes);
    scan_sums_kernel<<<1, 256, 0, stream>>>(fsums, foff, nSB, nNodes, nEdges);
    scan_write_kernel<<<nSB, 1024, 0, stream>>>(foff, fcur, fsums, nNodes);
    {
        const int blocksPerXcd = 256;
        fill_xcd_kernel<<<blocksPerXcd * NXCD, 256, 0, stream>>>(
            src, dst, fcur, fssrc, nEdges, nNodes, blocksPerXcd);
    }
    long long work = (long long)nNodes * 16;
    aggregate_kernel<<<(int)((work + 255) / 256), 256, 0, stream>>>(x, foff, fssrc, out, nNodes);
    mlp_reg_kernel<<<6250, 256, 0, stream>>>(out, W1, b1, W2, b2, out, nNodes);
}